// Round 8
// baseline (183.358 us; speedup 1.0000x reference)
//
#include <hip/hip_runtime.h>

// LBP block — single fused kernel, 1 output row per wave, high occupancy.
// block = 256 threads (4 waves) = (n, 4-row tile, group of 16 channels).
// __launch_bounds__(256,6): cap 85 VGPR -> 6 waves/SIMD (24 waves/CU) for
// latency hiding (R5/R7 showed the stall is latency, not inst count or DS).
// Each wave holds its 3 x-rows x 3 input channels in 9 float4 registers;
// halo columns via __shfl (lane-0/63 garbage feeds only zeroed borders);
// exp(w) via 2 uniform ds_read_b128 per channel. Regular float4 stores
// (nontemporal regressed in R7 — stores want L2 write-combining).
//
// Numerics (do not change): y = (x0*cw0 + x1*cw1) + x2*cw2 sequentially with
// FMA contraction OFF to match the numpy reference; (c - s > 0) == (c > s)
// exactly for finite floats; y recompute across waves is bit-identical.

typedef float vfloat4 __attribute__((ext_vector_type(4)));

__global__ __launch_bounds__(256, 6) void lbp_all(
    const float* __restrict__ x,
    const float* __restrict__ conv_w,
    const float* __restrict__ w,
    float* __restrict__ out)
{
#pragma clang fp contract(off)
    const int n    = blockIdx.z;
    const int og   = blockIdx.y;             // channels og*16 .. og*16+15
    const int tid  = threadIdx.x;
    const int lane = tid & 63;
    const int wv   = tid >> 6;               // wave 0..3
    const int col  = lane * 4;
    const int hrow = blockIdx.x * 4 + wv;    // wave's output row

    __shared__ float ews[128];               // exp(w) for this block's 16 ch
    if (tid < 128) ews[tid] = expf(w[og * 128 + tid]);

    const float* xn = x + (size_t)n * 3 * 65536;

    // x rows hrow-1..hrow+1 (clamped), 3 input channels, in registers.
    vfloat4 xr[3][3];
    #pragma unroll
    for (int r = 0; r < 3; ++r) {
        int row = hrow - 1 + r;
        row = row < 0 ? 0 : (row > 255 ? 255 : row);
        #pragma unroll
        for (int ch = 0; ch < 3; ++ch)
            xr[r][ch] = *(const vfloat4*)(xn + (ch * 256 + row) * 256 + col);
    }

    if (og == 0) {  // copy channels 0..2 (xr[1] = row hrow)
        #pragma unroll
        for (int ch = 0; ch < 3; ++ch)
            *(vfloat4*)(out + ((((size_t)n * 67 + ch) * 256 + hrow) * 256 + col)) = xr[1][ch];
    }

    __syncthreads();

    float* obase = out + ((((size_t)n * 67 + 3 + og * 16) * 256 + hrow) * 256 + col);
    const bool brow = (hrow == 0) | (hrow == 255);   // wave-uniform

    for (int oi = 0; oi < 16; ++oi) {
        const int o = og * 16 + oi;
        const float cw0 = conv_w[o * 3 + 0];
        const float cw1 = conv_w[o * 3 + 1];
        const float cw2 = conv_w[o * 3 + 2];

        float res[4];
        if (brow) {
            res[0] = res[1] = res[2] = res[3] = 0.f;
        } else {
            // Y[r][k] = y at row hrow-1+r, col (col-1+k), k=0..5; halo via shfl.
            float Y[3][6];
            #pragma unroll
            for (int r = 0; r < 3; ++r) {
                float yx, yy, yz, yw;
                yx = xr[r][0].x * cw0 + xr[r][1].x * cw1 + xr[r][2].x * cw2;
                yy = xr[r][0].y * cw0 + xr[r][1].y * cw1 + xr[r][2].y * cw2;
                yz = xr[r][0].z * cw0 + xr[r][1].z * cw1 + xr[r][2].z * cw2;
                yw = xr[r][0].w * cw0 + xr[r][1].w * cw1 + xr[r][2].w * cw2;
                Y[r][1] = yx; Y[r][2] = yy; Y[r][3] = yz; Y[r][4] = yw;
                Y[r][0] = __shfl_up(yw, 1);   // lane 0 garbage -> col 0 zeroed
                Y[r][5] = __shfl_down(yx, 1); // lane 63 garbage -> col 255 zeroed
            }

            const vfloat4 ev0 = *(const vfloat4*)&ews[oi * 8];
            const vfloat4 ev1 = *(const vfloat4*)&ews[oi * 8 + 4];
            const float e0 = ev0.x, e1 = ev0.y, e2 = ev0.z, e3 = ev0.w;
            const float e4 = ev1.x, e5 = ev1.y, e6 = ev1.z, e7 = ev1.w;

            #pragma unroll
            for (int j = 0; j < 4; ++j) {
                const float c = Y[1][j + 1];
                float acc;
                acc  = (c > Y[0][j    ]) ? e0 : 0.f;   // (-1,-1)
                acc += (c > Y[0][j + 1]) ? e1 : 0.f;   // (-1, 0)
                acc += (c > Y[0][j + 2]) ? e2 : 0.f;   // (-1,+1)
                acc += (c > Y[1][j    ]) ? e3 : 0.f;   // ( 0,-1)
                acc += (c > Y[2][j    ]) ? e4 : 0.f;   // (+1,-1)
                acc += (c > Y[2][j + 1]) ? e5 : 0.f;   // (+1, 0)
                acc += (c > Y[2][j + 2]) ? e6 : 0.f;   // (+1,+1)
                acc += (c > Y[1][j + 2]) ? e7 : 0.f;   // ( 0,+1)
                res[j] = acc;
            }
            if (lane == 0)  res[0] = 0.f;   // col 0
            if (lane == 63) res[3] = 0.f;   // col 255
        }

        vfloat4 rv; rv.x = res[0]; rv.y = res[1]; rv.z = res[2]; rv.w = res[3];
        *(vfloat4*)(obase + (size_t)oi * 65536) = rv;
    }
}

extern "C" void kernel_launch(void* const* d_in, const int* in_sizes, int n_in,
                              void* d_out, int out_size, void* d_ws, size_t ws_size,
                              hipStream_t stream) {
    const float* x      = (const float*)d_in[0];
    const float* conv_w = (const float*)d_in[1];
    const float* w      = (const float*)d_in[2];
    float* out          = (float*)d_out;

    dim3 grid(64, 4, 8);   // (4-row tiles, channel groups of 16, batch)
    dim3 block(256);
    hipLaunchKernelGGL(lbp_all, grid, block, 0, stream, x, conv_w, w, out);
}

// Round 9
// 154.091 us; speedup vs baseline: 1.1899x; 1.1899x over previous
//
#include <hip/hip_runtime.h>

// LBP block — single fused kernel, 4 output rows per wave.
// block = 256 threads (4 waves); block covers (n, 16-row tile, 8 channels).
// Wave wv owns output rows h0..h0+3 (h0 = bx*16 + wv*4): its 6 x-rows x 3
// input channels live in 18 float4 registers; 6 y-rows serve 4 output rows
// (1.5x y redundancy). Per channel: one long VALU stream, then 4 stores
// covering 4KB contiguous. Halo via __shfl; exp(w) via uniform ds_read_b128.
// No VGPR cap (R8 showed __launch_bounds__ min-waves caps starve the
// allocator); plain float4 stores (nontemporal regressed in R7).
//
// Numerics (do not change): y = (x0*cw0 + x1*cw1) + x2*cw2 sequentially with
// FMA contraction OFF to match the numpy reference; (c - s > 0) == (c > s)
// exactly for finite floats; y recompute across waves/blocks is bit-identical
// (same expression, same inputs). Lane-0/63 halo garbage feeds only border
// columns, which are zeroed; border rows are zeroed wave-uniformly.

typedef float vfloat4 __attribute__((ext_vector_type(4)));

__global__ __launch_bounds__(256) void lbp_all(
    const float* __restrict__ x,
    const float* __restrict__ conv_w,
    const float* __restrict__ w,
    float* __restrict__ out)
{
#pragma clang fp contract(off)
    const int n    = blockIdx.z;
    const int og   = blockIdx.y;             // channels og*8 .. og*8+7
    const int tid  = threadIdx.x;
    const int lane = tid & 63;
    const int wv   = tid >> 6;               // wave 0..3
    const int col  = lane * 4;
    const int h0   = blockIdx.x * 16 + wv * 4;   // wave's first output row

    __shared__ float ews[64];                // exp(w) for this block's 8 ch
    if (tid < 64) ews[tid] = expf(w[og * 64 + tid]);

    const float* xn = x + (size_t)n * 3 * 65536;

    // x rows h0-1 .. h0+4 (clamped), 3 input channels, in registers.
    vfloat4 xr[6][3];
    #pragma unroll
    for (int r = 0; r < 6; ++r) {
        int row = h0 - 1 + r;
        row = row < 0 ? 0 : (row > 255 ? 255 : row);
        #pragma unroll
        for (int ch = 0; ch < 3; ++ch)
            xr[r][ch] = *(const vfloat4*)(xn + (ch * 256 + row) * 256 + col);
    }

    if (og == 0) {  // copy channels 0..2; xr[k+1] = input row h0+k
        #pragma unroll
        for (int ch = 0; ch < 3; ++ch) {
            float* cp = out + ((((size_t)n * 67 + ch) * 256 + h0) * 256 + col);
            #pragma unroll
            for (int k = 0; k < 4; ++k)
                *(vfloat4*)(cp + (size_t)k * 256) = xr[k + 1][ch];
        }
    }

    __syncthreads();

    float* obase = out + ((((size_t)n * 67 + 3 + og * 8) * 256 + h0) * 256 + col);

    for (int oi = 0; oi < 8; ++oi) {
        const int o = og * 8 + oi;
        const float cw0 = conv_w[o * 3 + 0];
        const float cw1 = conv_w[o * 3 + 1];
        const float cw2 = conv_w[o * 3 + 2];

        // Y[r][k] = y at row h0-1+r, col (col-1+k), k=0..5; halo via shfl.
        float Y[6][6];
        #pragma unroll
        for (int r = 0; r < 6; ++r) {
            float yx, yy, yz, yw;
            yx = xr[r][0].x * cw0 + xr[r][1].x * cw1 + xr[r][2].x * cw2;
            yy = xr[r][0].y * cw0 + xr[r][1].y * cw1 + xr[r][2].y * cw2;
            yz = xr[r][0].z * cw0 + xr[r][1].z * cw1 + xr[r][2].z * cw2;
            yw = xr[r][0].w * cw0 + xr[r][1].w * cw1 + xr[r][2].w * cw2;
            Y[r][1] = yx; Y[r][2] = yy; Y[r][3] = yz; Y[r][4] = yw;
            Y[r][0] = __shfl_up(yw, 1);   // lane 0 garbage -> col 0 zeroed
            Y[r][5] = __shfl_down(yx, 1); // lane 63 garbage -> col 255 zeroed
        }

        const vfloat4 ev0 = *(const vfloat4*)&ews[oi * 8];     // uniform addr
        const vfloat4 ev1 = *(const vfloat4*)&ews[oi * 8 + 4]; // -> 2x b128
        const float e0 = ev0.x, e1 = ev0.y, e2 = ev0.z, e3 = ev0.w;
        const float e4 = ev1.x, e5 = ev1.y, e6 = ev1.z, e7 = ev1.w;

        #pragma unroll
        for (int k = 0; k < 4; ++k) {        // the wave's four output rows
            const int hrow = h0 + k;
            float res[4];
            if (hrow == 0 || hrow == 255) {  // wave-uniform branch
                res[0] = res[1] = res[2] = res[3] = 0.f;
            } else {
                const float* up  = Y[k];
                const float* mid = Y[k + 1];
                const float* dn  = Y[k + 2];
                #pragma unroll
                for (int j = 0; j < 4; ++j) {
                    const float c = mid[j + 1];
                    float acc;
                    acc  = (c > up [j    ]) ? e0 : 0.f;   // (-1,-1)
                    acc += (c > up [j + 1]) ? e1 : 0.f;   // (-1, 0)
                    acc += (c > up [j + 2]) ? e2 : 0.f;   // (-1,+1)
                    acc += (c > mid[j    ]) ? e3 : 0.f;   // ( 0,-1)
                    acc += (c > dn [j    ]) ? e4 : 0.f;   // (+1,-1)
                    acc += (c > dn [j + 1]) ? e5 : 0.f;   // (+1, 0)
                    acc += (c > dn [j + 2]) ? e6 : 0.f;   // (+1,+1)
                    acc += (c > mid[j + 2]) ? e7 : 0.f;   // ( 0,+1)
                    res[j] = acc;
                }
                if (lane == 0)  res[0] = 0.f;   // col 0
                if (lane == 63) res[3] = 0.f;   // col 255
            }
            vfloat4 rv; rv.x = res[0]; rv.y = res[1]; rv.z = res[2]; rv.w = res[3];
            *(vfloat4*)(obase + (size_t)oi * 65536 + (size_t)k * 256) = rv;
        }
    }
}

extern "C" void kernel_launch(void* const* d_in, const int* in_sizes, int n_in,
                              void* d_out, int out_size, void* d_ws, size_t ws_size,
                              hipStream_t stream) {
    const float* x      = (const float*)d_in[0];
    const float* conv_w = (const float*)d_in[1];
    const float* w      = (const float*)d_in[2];
    float* out          = (float*)d_out;

    dim3 grid(16, 8, 8);   // (16-row tiles, channel groups of 8, batch)
    dim3 block(256);
    hipLaunchKernelGGL(lbp_all, grid, block, 0, stream, x, conv_w, w, out);
}